// Round 11
// baseline (452.771 us; speedup 1.0000x reference)
//
#include <hip/hip_runtime.h>
#include <hip/hip_bf16.h>
#include <math.h>

typedef short short8 __attribute__((ext_vector_type(8)));
typedef short short4v __attribute__((ext_vector_type(4)));
typedef float f32x4 __attribute__((ext_vector_type(4)));

__device__ inline void bsplit(float x, short& h, short& l) {
    __hip_bfloat16 hb = __float2bfloat16(x);
    float hf = __bfloat162float(hb);
    __hip_bfloat16 lb = __float2bfloat16(x - hf);
    h = *reinterpret_cast<short*>(&hb);
    l = *reinterpret_cast<short*>(&lb);
}

// ---------------- CSR build ----------------

__global__ void zero_i32(int* __restrict__ p, int n) {
    int i = blockIdx.x * blockDim.x + threadIdx.x;
    if (i < n) p[i] = 0;
}

__global__ void hist_kernel(const int* __restrict__ row, int* __restrict__ hist, int E) {
    int i = blockIdx.x * blockDim.x + threadIdx.x;
    if (i < E) atomicAdd(&hist[row[i]], 1);
}

// single-block scan, wave-shuffle version
__global__ void scan_kernel(const int* __restrict__ hist, int* __restrict__ rowptr,
                            int* __restrict__ cursor, int n) {
    __shared__ int wsum[16];
    __shared__ int carry_s;
    int tid = threadIdx.x, lane = tid & 63, wid = tid >> 6;
    if (tid == 0) { carry_s = 0; rowptr[0] = 0; }
    __syncthreads();
    for (int base = 0; base < n; base += 1024) {
        int idx = base + tid;
        int v = (idx < n) ? hist[idx] : 0;
        int x = v;
#pragma unroll
        for (int d = 1; d < 64; d <<= 1) {
            int t = __shfl_up(x, d, 64);
            if (lane >= d) x += t;
        }
        if (lane == 63) wsum[wid] = x;
        __syncthreads();
        if (wid == 0) {
            int s = (lane < 16) ? wsum[lane] : 0;
#pragma unroll
            for (int d = 1; d < 16; d <<= 1) {
                int t = __shfl_up(s, d, 64);
                if (lane >= d) s += t;
            }
            if (lane < 16) wsum[lane] = s;
        }
        __syncthreads();
        int woff = (wid > 0) ? wsum[wid - 1] : 0;
        int inc = x + woff + carry_s;
        if (idx < n) {
            rowptr[idx + 1] = inc;
            cursor[idx] = inc - v;
        }
        __syncthreads();
        if (tid == 1023) carry_s = inc;
        __syncthreads();
    }
}

__global__ void scatter_kernel(const int* __restrict__ row, const int* __restrict__ col,
                               const float* __restrict__ val, int* __restrict__ cursor,
                               int* __restrict__ colsort, float* __restrict__ valsort, int E) {
    int i = blockIdx.x * blockDim.x + threadIdx.x;
    if (i < E) {
        int r = row[i];
        int p = atomicAdd(&cursor[r], 1);
        colsort[p] = col[i];
        valsort[p] = val[i];
    }
}

// ---------------- dense layer GEMM: out[n,M] = A[n,K] @ W[K,M] ----------------
template <int K, int M>
__global__ void gemm_layer(const float* __restrict__ A, const float* __restrict__ W,
                           float* __restrict__ out, int n) {
    __shared__ float a[8 * K];
    int j = threadIdx.x;
    int row0 = blockIdx.x * 8;
    constexpr int K4 = K / 4;
    for (int idx = j; idx < 8 * K4; idx += M) {
        int r = idx / K4, k4 = idx % K4;
        float4 v = make_float4(0.f, 0.f, 0.f, 0.f);
        if (row0 + r < n) v = *reinterpret_cast<const float4*>(A + (long)(row0 + r) * K + k4 * 4);
        *reinterpret_cast<float4*>(a + r * K + k4 * 4) = v;
    }
    __syncthreads();
    float acc[8] = {0, 0, 0, 0, 0, 0, 0, 0};
#pragma unroll 8
    for (int k = 0; k < K; k++) {
        float w = W[k * M + j];
#pragma unroll
        for (int r = 0; r < 8; r++) acc[r] += a[r * K + k] * w;
    }
#pragma unroll
    for (int r = 0; r < 8; r++) {
        if (row0 + r < n) out[(long)(row0 + r) * M + j] = acc[r];
    }
}

// ---------------- head GEMM with fused bf16 hi/lo split: T = h3 @ S ----------------
__global__ void gemm_head(const float* __restrict__ A, const float* __restrict__ S,
                          short* __restrict__ Th, short* __restrict__ Tl, int n) {
    __shared__ float a[8 * 64];
    int j = threadIdx.x;   // 0..63
    int row0 = blockIdx.x * 8;
    for (int idx = j; idx < 8 * 16; idx += 64) {
        int r = idx >> 4, k4 = idx & 15;
        float4 v = make_float4(0.f, 0.f, 0.f, 0.f);
        if (row0 + r < n) v = *reinterpret_cast<const float4*>(A + (long)(row0 + r) * 64 + k4 * 4);
        *reinterpret_cast<float4*>(a + r * 64 + k4 * 4) = v;
    }
    __syncthreads();
    float acc[8] = {0, 0, 0, 0, 0, 0, 0, 0};
#pragma unroll 8
    for (int k = 0; k < 64; k++) {
        float w = S[k * 64 + j];
#pragma unroll
        for (int r = 0; r < 8; r++) acc[r] += a[r * 64 + k] * w;
    }
#pragma unroll
    for (int r = 0; r < 8; r++) {
        if (row0 + r < n) {
            short h, l;
            bsplit(acc[r], h, l);
            Th[(long)(row0 + r) * 64 + j] = h;
            Tl[(long)(row0 + r) * 64 + j] = l;
        }
    }
}

// ---------------- SpMM over a 64-wide feature half ----------------
__global__ void spmm_elu_half(const int* __restrict__ rowptr, const int* __restrict__ cols,
                              const float* __restrict__ vals, const float* __restrict__ hw,
                              int tstride, float* __restrict__ out, int ostride, int n) {
    constexpr int LPR = 16, EPI = 4;
    int wave = (blockIdx.x * blockDim.x + threadIdx.x) >> 6;
    int lane = threadIdx.x & 63;
    if (wave >= n) return;
    int sub = lane % LPR, grp = lane / LPR;
    int s = rowptr[wave], e = rowptr[wave + 1];
    float ax = 0.f, ay = 0.f, az = 0.f, aw = 0.f;
    int pe = s + grp;
    int c = 0; float v = 0.f;
    if (pe < e) { c = cols[pe]; v = vals[pe]; }
    for (int p = s; p < e; p += EPI) {
        int pn = p + EPI + grp;
        int cn = 0; float vn = 0.f;
        if (pn < e) { cn = cols[pn]; vn = vals[pn]; }
        float4 h4 = *reinterpret_cast<const float4*>(hw + (long)c * tstride + sub * 4);
        ax += v * h4.x; ay += v * h4.y; az += v * h4.z; aw += v * h4.w;
        c = cn; v = vn;
    }
#pragma unroll
    for (int m = LPR; m < 64; m <<= 1) {
        ax += __shfl_xor(ax, m, 64);
        ay += __shfl_xor(ay, m, 64);
        az += __shfl_xor(az, m, 64);
        aw += __shfl_xor(aw, m, 64);
    }
    if (grp == 0) {
        float4 o;
        o.x = ax > 0.f ? ax : (__expf(ax) - 1.f);
        o.y = ay > 0.f ? ay : (__expf(ay) - 1.f);
        o.z = az > 0.f ? az : (__expf(az) - 1.f);
        o.w = aw > 0.f ? aw : (__expf(aw) - 1.f);
        *reinterpret_cast<float4*>(out + (long)wave * ostride + sub * 4) = o;
    }
}

// D=64 variant with fused bf16 hi/lo split for the head's B operand
__global__ void spmm_elu_split64(const int* __restrict__ rowptr, const int* __restrict__ cols,
                                 const float* __restrict__ vals, const float* __restrict__ hw,
                                 float* __restrict__ h3, short* __restrict__ Hh,
                                 short* __restrict__ Hl, int n) {
    constexpr int D = 64, LPR = 16, EPI = 4;
    int wave = (blockIdx.x * blockDim.x + threadIdx.x) >> 6;
    int lane = threadIdx.x & 63;
    if (wave >= n) return;
    int sub = lane % LPR, grp = lane / LPR;
    int s = rowptr[wave], e = rowptr[wave + 1];
    float ax = 0.f, ay = 0.f, az = 0.f, aw = 0.f;
    int pe = s + grp;
    int c = 0; float v = 0.f;
    if (pe < e) { c = cols[pe]; v = vals[pe]; }
    for (int p = s; p < e; p += EPI) {
        int pn = p + EPI + grp;
        int cn = 0; float vn = 0.f;
        if (pn < e) { cn = cols[pn]; vn = vals[pn]; }
        float4 h4 = *reinterpret_cast<const float4*>(hw + (long)c * D + sub * 4);
        ax += v * h4.x; ay += v * h4.y; az += v * h4.z; aw += v * h4.w;
        c = cn; v = vn;
    }
#pragma unroll
    for (int m = LPR; m < 64; m <<= 1) {
        ax += __shfl_xor(ax, m, 64);
        ay += __shfl_xor(ay, m, 64);
        az += __shfl_xor(az, m, 64);
        aw += __shfl_xor(aw, m, 64);
    }
    if (grp == 0) {
        float4 o;
        o.x = ax > 0.f ? ax : (__expf(ax) - 1.f);
        o.y = ay > 0.f ? ay : (__expf(ay) - 1.f);
        o.z = az > 0.f ? az : (__expf(az) - 1.f);
        o.w = aw > 0.f ? aw : (__expf(aw) - 1.f);
        *reinterpret_cast<float4*>(h3 + (long)wave * D + sub * 4) = o;
        short4v hs, ls;
        short t0, t1, t2, t3, u0, u1, u2, u3;
        bsplit(o.x, t0, u0);
        bsplit(o.y, t1, u1);
        bsplit(o.z, t2, u2);
        bsplit(o.w, t3, u3);
        hs[0] = t0; hs[1] = t1; hs[2] = t2; hs[3] = t3;
        ls[0] = u0; ls[1] = u1; ls[2] = u2; ls[3] = u3;
        *reinterpret_cast<short4v*>(Hh + (long)wave * D + sub * 4) = hs;
        *reinterpret_cast<short4v*>(Hl + (long)wave * D + sub * 4) = ls;
    }
}

// ---------------- S = (Wb + Wb^T)/2 ----------------
__global__ void sym_kernel(const float* __restrict__ Wb, float* __restrict__ S) {
    int i = blockIdx.x * blockDim.x + threadIdx.x;
    if (i < 64 * 64) {
        int r = i >> 6, c = i & 63;
        S[i] = 0.5f * (Wb[r * 64 + c] + Wb[c * 64 + r]);
    }
}

// ---------------- zero the padded rows of the bf16 operands ----------------
__global__ void pad_zero(short* __restrict__ Th, short* __restrict__ Tl,
                         short* __restrict__ Hh, short* __restrict__ Hl,
                         int startRow, int padRows) {
    int i = blockIdx.x * blockDim.x + threadIdx.x;
    int tot = padRows * 64;
    if (i < tot) {
        long off = (long)startRow * 64 + i;
        Th[off] = 0; Tl[off] = 0; Hh[off] = 0; Hl[off] = 0;
    }
}

// ---------------- final: out = sigmoid(T @ H^T) via split-bf16 MFMA ----------------
__global__ __launch_bounds__(256, 2) void final_mfma(
    const short* __restrict__ Th, const short* __restrict__ Tl,
    const short* __restrict__ Hh, const short* __restrict__ Hl,
    float* __restrict__ out, int n, int G, int ypx) {
    int bid = blockIdx.x;
    int xcd = bid & 7;
    int s4 = bid >> 3;
    int by = xcd * ypx + s4 % ypx;
    int bx = s4 / ypx;
    if (by >= G) return;

    int tid = threadIdx.x;
    int wave = tid >> 6, lane = tid & 63;
    int row0 = by * 128 + (wave >> 1) * 64;
    int col0 = bx * 128 + (wave & 1) * 64;
    int lrow = lane & 15;
    int koff = (lane >> 4) * 8;

    const short* ThB = Th + (long)(row0 + lrow) * 64 + koff;
    const short* TlB = Tl + (long)(row0 + lrow) * 64 + koff;
    const short* HhB = Hh + (long)(col0 + lrow) * 64 + koff;
    const short* HlB = Hl + (long)(col0 + lrow) * 64 + koff;

    f32x4 acc[4][4];
#pragma unroll
    for (int r = 0; r < 4; r++)
#pragma unroll
        for (int c = 0; c < 4; c++) acc[r][c] = (f32x4){0.f, 0.f, 0.f, 0.f};

#pragma unroll
    for (int ks = 0; ks < 2; ks++) {
        int kb = ks * 32;
        short8 ah[4], al[4];
#pragma unroll
        for (int r = 0; r < 4; r++) ah[r] = *reinterpret_cast<const short8*>(ThB + (long)(r * 16) * 64 + kb);
#pragma unroll
        for (int r = 0; r < 4; r++) al[r] = *reinterpret_cast<const short8*>(TlB + (long)(r * 16) * 64 + kb);

#pragma unroll
        for (int c = 0; c < 4; c++) {
            short8 bh = *reinterpret_cast<const short8*>(HhB + (long)(c * 16) * 64 + kb);
            short8 bl = *reinterpret_cast<const short8*>(HlB + (long)(c * 16) * 64 + kb);
#pragma unroll
            for (int r = 0; r < 4; r++)
                acc[r][c] = __builtin_amdgcn_mfma_f32_16x16x32_bf16(ah[r], bh, acc[r][c], 0, 0, 0);
#pragma unroll
            for (int r = 0; r < 4; r++)
                acc[r][c] = __builtin_amdgcn_mfma_f32_16x16x32_bf16(ah[r], bl, acc[r][c], 0, 0, 0);
#pragma unroll
            for (int r = 0; r < 4; r++)
                acc[r][c] = __builtin_amdgcn_mfma_f32_16x16x32_bf16(al[r], bh, acc[r][c], 0, 0, 0);
        }
    }

    // epilogue: C/D layout col = lane&15, row = (lane>>4)*4 + reg  [m89-verified]
    int orow = (lane >> 4) * 4;
    bool full = (row0 + 64 <= n) && (col0 + 64 <= n);
    if (full) {
#pragma unroll
        for (int r = 0; r < 4; r++) {
#pragma unroll
            for (int q = 0; q < 4; q++) {
                long base = (long)(row0 + r * 16 + orow + q) * n + col0 + lrow;
#pragma unroll
                for (int c = 0; c < 4; c++) {
                    float x = acc[r][c][q];
                    out[base + c * 16] = __builtin_amdgcn_rcpf(1.f + __expf(-x));
                }
            }
        }
    } else {
#pragma unroll
        for (int r = 0; r < 4; r++) {
#pragma unroll
            for (int q = 0; q < 4; q++) {
                int i = row0 + r * 16 + orow + q;
                if (i < n) {
#pragma unroll
                    for (int c = 0; c < 4; c++) {
                        int j = col0 + c * 16 + lrow;
                        if (j < n) {
                            float x = acc[r][c][q];
                            out[(long)i * n + j] = __builtin_amdgcn_rcpf(1.f + __expf(-x));
                        }
                    }
                }
            }
        }
    }
}

// ---------------- launch ----------------
extern "C" void kernel_launch(void* const* d_in, const int* in_sizes, int n_in,
                              void* d_out, int out_size, void* d_ws, size_t ws_size,
                              hipStream_t stream) {
    const float* x    = (const float*)d_in[0];
    const int*   erow = (const int*)d_in[1];
    const int*   ecol = (const int*)d_in[2];
    const float* eval = (const float*)d_in[3];
    const float* W0   = (const float*)d_in[4];
    const float* W1   = (const float*)d_in[5];
    const float* W2   = (const float*)d_in[6];
    const float* Wb   = (const float*)d_in[7];
    float* out = (float*)d_out;

    int N = in_sizes[0] / 128;
    int E = in_sizes[1];
    int G = (N + 127) / 128;
    int Npad = G * 128;

    char* w = (char*)d_ws;
    size_t off = 0;
    auto alloc = [&](size_t bytes) -> void* {
        void* p = w + off;
        off += (bytes + 255) & ~(size_t)255;
        return p;
    };
    float* bufA    = (float*)alloc((size_t)N * 128 * 4);
    float* bufB    = (float*)alloc((size_t)N * 128 * 4);
    float* h3      = (float*)alloc((size_t)N * 64 * 4);
    float* S       = (float*)alloc(64 * 64 * 4);
    int*   colsort = (int*)alloc((size_t)E * 4);
    float* valsort = (float*)alloc((size_t)E * 4);
    int*   rowptr  = (int*)alloc((size_t)(N + 1) * 4);
    int*   cursor  = (int*)alloc((size_t)N * 4);
    int*   hist    = (int*)alloc((size_t)N * 4);
    short* Th      = (short*)alloc((size_t)Npad * 64 * 2);
    short* Tl      = (short*)alloc((size_t)Npad * 64 * 2);
    short* Hh      = (short*)alloc((size_t)Npad * 64 * 2);
    short* Hl      = (short*)alloc((size_t)Npad * 64 * 2);

    // CSR build
    zero_i32<<<(N + 255) / 256, 256, 0, stream>>>(hist, N);
    hist_kernel<<<(E + 255) / 256, 256, 0, stream>>>(erow, hist, E);
    scan_kernel<<<1, 1024, 0, stream>>>(hist, rowptr, cursor, N);
    scatter_kernel<<<(E + 255) / 256, 256, 0, stream>>>(erow, ecol, eval, cursor, colsort, valsort, E);

    int gb8 = (N + 7) / 8;
    int spmmG = (N + 3) / 4;
    // layer 1
    gemm_layer<128, 128><<<gb8, 128, 0, stream>>>(x, W0, bufB, N);
    spmm_elu_half<<<spmmG, 256, 0, stream>>>(rowptr, colsort, valsort, bufB, 128, bufA, 128, N);
    spmm_elu_half<<<spmmG, 256, 0, stream>>>(rowptr, colsort, valsort, bufB + 64, 128, bufA + 64, 128, N);
    // layer 2
    gemm_layer<128, 128><<<gb8, 128, 0, stream>>>(bufA, W1, bufB, N);
    spmm_elu_half<<<spmmG, 256, 0, stream>>>(rowptr, colsort, valsort, bufB, 128, bufA, 128, N);
    spmm_elu_half<<<spmmG, 256, 0, stream>>>(rowptr, colsort, valsort, bufB + 64, 128, bufA + 64, 128, N);
    // layer 3 (128 -> 64)
    gemm_layer<128, 64><<<gb8, 64, 0, stream>>>(bufA, W2, bufB, N);
    spmm_elu_split64<<<spmmG, 256, 0, stream>>>(rowptr, colsort, valsort, bufB, h3, Hh, Hl, N);

    sym_kernel<<<16, 256, 0, stream>>>(Wb, S);
    gemm_head<<<gb8, 64, 0, stream>>>(h3, S, Th, Tl, N);

    int padRows = Npad - N;
    if (padRows > 0)
        pad_zero<<<(padRows * 64 + 255) / 256, 256, 0, stream>>>(Th, Tl, Hh, Hl, N, padRows);

    int ypx = (G + 7) / 8;                 // y-tiles per XCD band
    int nwg = 8 * ypx * G;                 // padded; blocks with by>=G early-exit
    // ABLATION (R11): launch final twice; second write is idempotent.
    // Delta dur_us vs R10 = direct measurement of final_mfma's cost.
    final_mfma<<<nwg, 256, 0, stream>>>(Th, Tl, Hh, Hl, out, N, G, ypx);
    final_mfma<<<nwg, 256, 0, stream>>>(Th, Tl, Hh, Hl, out, N, G, ypx);
}

// Round 12
// 292.567 us; speedup vs baseline: 1.5476x; 1.5476x over previous
//
#include <hip/hip_runtime.h>
#include <hip/hip_bf16.h>
#include <math.h>

typedef short short8 __attribute__((ext_vector_type(8)));
typedef short short4v __attribute__((ext_vector_type(4)));
typedef float f32x4 __attribute__((ext_vector_type(4)));

__device__ inline void bsplit(float x, short& h, short& l) {
    __hip_bfloat16 hb = __float2bfloat16(x);
    float hf = __bfloat162float(hb);
    __hip_bfloat16 lb = __float2bfloat16(x - hf);
    h = *reinterpret_cast<short*>(&hb);
    l = *reinterpret_cast<short*>(&lb);
}

// ---------------- CSR build ----------------

__global__ void zero_i32(int* __restrict__ p, int n) {
    int i = blockIdx.x * blockDim.x + threadIdx.x;
    if (i < n) p[i] = 0;
}

__global__ void hist_kernel(const int* __restrict__ row, int* __restrict__ hist, int E) {
    int i = blockIdx.x * blockDim.x + threadIdx.x;
    if (i < E) atomicAdd(&hist[row[i]], 1);
}

// single-block scan, wave-shuffle version
__global__ void scan_kernel(const int* __restrict__ hist, int* __restrict__ rowptr,
                            int* __restrict__ cursor, int n) {
    __shared__ int wsum[16];
    __shared__ int carry_s;
    int tid = threadIdx.x, lane = tid & 63, wid = tid >> 6;
    if (tid == 0) { carry_s = 0; rowptr[0] = 0; }
    __syncthreads();
    for (int base = 0; base < n; base += 1024) {
        int idx = base + tid;
        int v = (idx < n) ? hist[idx] : 0;
        int x = v;
#pragma unroll
        for (int d = 1; d < 64; d <<= 1) {
            int t = __shfl_up(x, d, 64);
            if (lane >= d) x += t;
        }
        if (lane == 63) wsum[wid] = x;
        __syncthreads();
        if (wid == 0) {
            int s = (lane < 16) ? wsum[lane] : 0;
#pragma unroll
            for (int d = 1; d < 16; d <<= 1) {
                int t = __shfl_up(s, d, 64);
                if (lane >= d) s += t;
            }
            if (lane < 16) wsum[lane] = s;
        }
        __syncthreads();
        int woff = (wid > 0) ? wsum[wid - 1] : 0;
        int inc = x + woff + carry_s;
        if (idx < n) {
            rowptr[idx + 1] = inc;
            cursor[idx] = inc - v;
        }
        __syncthreads();
        if (tid == 1023) carry_s = inc;
        __syncthreads();
    }
}

__global__ void scatter_kernel(const int* __restrict__ row, const int* __restrict__ col,
                               const float* __restrict__ val, int* __restrict__ cursor,
                               int* __restrict__ colsort, float* __restrict__ valsort, int E) {
    int i = blockIdx.x * blockDim.x + threadIdx.x;
    if (i < E) {
        int r = row[i];
        int p = atomicAdd(&cursor[r], 1);
        colsort[p] = col[i];
        valsort[p] = val[i];
    }
}

// ---------------- dense layer GEMM: out[n,M] = A[n,K] @ W[K,M] ----------------
template <int K, int M>
__global__ void gemm_layer(const float* __restrict__ A, const float* __restrict__ W,
                           float* __restrict__ out, int n) {
    __shared__ float a[8 * K];
    int j = threadIdx.x;
    int row0 = blockIdx.x * 8;
    constexpr int K4 = K / 4;
    for (int idx = j; idx < 8 * K4; idx += M) {
        int r = idx / K4, k4 = idx % K4;
        float4 v = make_float4(0.f, 0.f, 0.f, 0.f);
        if (row0 + r < n) v = *reinterpret_cast<const float4*>(A + (long)(row0 + r) * K + k4 * 4);
        *reinterpret_cast<float4*>(a + r * K + k4 * 4) = v;
    }
    __syncthreads();
    float acc[8] = {0, 0, 0, 0, 0, 0, 0, 0};
#pragma unroll 8
    for (int k = 0; k < K; k++) {
        float w = W[k * M + j];
#pragma unroll
        for (int r = 0; r < 8; r++) acc[r] += a[r * K + k] * w;
    }
#pragma unroll
    for (int r = 0; r < 8; r++) {
        if (row0 + r < n) out[(long)(row0 + r) * M + j] = acc[r];
    }
}

// ---------------- head GEMM with fused bf16 hi/lo split: T = h3 @ S ----------------
__global__ void gemm_head(const float* __restrict__ A, const float* __restrict__ S,
                          short* __restrict__ Th, short* __restrict__ Tl, int n) {
    __shared__ float a[8 * 64];
    int j = threadIdx.x;   // 0..63
    int row0 = blockIdx.x * 8;
    for (int idx = j; idx < 8 * 16; idx += 64) {
        int r = idx >> 4, k4 = idx & 15;
        float4 v = make_float4(0.f, 0.f, 0.f, 0.f);
        if (row0 + r < n) v = *reinterpret_cast<const float4*>(A + (long)(row0 + r) * 64 + k4 * 4);
        *reinterpret_cast<float4*>(a + r * 64 + k4 * 4) = v;
    }
    __syncthreads();
    float acc[8] = {0, 0, 0, 0, 0, 0, 0, 0};
#pragma unroll 8
    for (int k = 0; k < 64; k++) {
        float w = S[k * 64 + j];
#pragma unroll
        for (int r = 0; r < 8; r++) acc[r] += a[r * 64 + k] * w;
    }
#pragma unroll
    for (int r = 0; r < 8; r++) {
        if (row0 + r < n) {
            short h, l;
            bsplit(acc[r], h, l);
            Th[(long)(row0 + r) * 64 + j] = h;
            Tl[(long)(row0 + r) * 64 + j] = l;
        }
    }
}

// ---------------- SpMM over a 64-wide feature half ----------------
__global__ void spmm_elu_half(const int* __restrict__ rowptr, const int* __restrict__ cols,
                              const float* __restrict__ vals, const float* __restrict__ hw,
                              int tstride, float* __restrict__ out, int ostride, int n) {
    constexpr int LPR = 16, EPI = 4;
    int wave = (blockIdx.x * blockDim.x + threadIdx.x) >> 6;
    int lane = threadIdx.x & 63;
    if (wave >= n) return;
    int sub = lane % LPR, grp = lane / LPR;
    int s = rowptr[wave], e = rowptr[wave + 1];
    float ax = 0.f, ay = 0.f, az = 0.f, aw = 0.f;
    int pe = s + grp;
    int c = 0; float v = 0.f;
    if (pe < e) { c = cols[pe]; v = vals[pe]; }
    for (int p = s; p < e; p += EPI) {
        int pn = p + EPI + grp;
        int cn = 0; float vn = 0.f;
        if (pn < e) { cn = cols[pn]; vn = vals[pn]; }
        float4 h4 = *reinterpret_cast<const float4*>(hw + (long)c * tstride + sub * 4);
        ax += v * h4.x; ay += v * h4.y; az += v * h4.z; aw += v * h4.w;
        c = cn; v = vn;
    }
#pragma unroll
    for (int m = LPR; m < 64; m <<= 1) {
        ax += __shfl_xor(ax, m, 64);
        ay += __shfl_xor(ay, m, 64);
        az += __shfl_xor(az, m, 64);
        aw += __shfl_xor(aw, m, 64);
    }
    if (grp == 0) {
        float4 o;
        o.x = ax > 0.f ? ax : (__expf(ax) - 1.f);
        o.y = ay > 0.f ? ay : (__expf(ay) - 1.f);
        o.z = az > 0.f ? az : (__expf(az) - 1.f);
        o.w = aw > 0.f ? aw : (__expf(aw) - 1.f);
        *reinterpret_cast<float4*>(out + (long)wave * ostride + sub * 4) = o;
    }
}

// D=64 variant with fused bf16 hi/lo split for the head's B operand
__global__ void spmm_elu_split64(const int* __restrict__ rowptr, const int* __restrict__ cols,
                                 const float* __restrict__ vals, const float* __restrict__ hw,
                                 float* __restrict__ h3, short* __restrict__ Hh,
                                 short* __restrict__ Hl, int n) {
    constexpr int D = 64, LPR = 16, EPI = 4;
    int wave = (blockIdx.x * blockDim.x + threadIdx.x) >> 6;
    int lane = threadIdx.x & 63;
    if (wave >= n) return;
    int sub = lane % LPR, grp = lane / LPR;
    int s = rowptr[wave], e = rowptr[wave + 1];
    float ax = 0.f, ay = 0.f, az = 0.f, aw = 0.f;
    int pe = s + grp;
    int c = 0; float v = 0.f;
    if (pe < e) { c = cols[pe]; v = vals[pe]; }
    for (int p = s; p < e; p += EPI) {
        int pn = p + EPI + grp;
        int cn = 0; float vn = 0.f;
        if (pn < e) { cn = cols[pn]; vn = vals[pn]; }
        float4 h4 = *reinterpret_cast<const float4*>(hw + (long)c * D + sub * 4);
        ax += v * h4.x; ay += v * h4.y; az += v * h4.z; aw += v * h4.w;
        c = cn; v = vn;
    }
#pragma unroll
    for (int m = LPR; m < 64; m <<= 1) {
        ax += __shfl_xor(ax, m, 64);
        ay += __shfl_xor(ay, m, 64);
        az += __shfl_xor(az, m, 64);
        aw += __shfl_xor(aw, m, 64);
    }
    if (grp == 0) {
        float4 o;
        o.x = ax > 0.f ? ax : (__expf(ax) - 1.f);
        o.y = ay > 0.f ? ay : (__expf(ay) - 1.f);
        o.z = az > 0.f ? az : (__expf(az) - 1.f);
        o.w = aw > 0.f ? aw : (__expf(aw) - 1.f);
        *reinterpret_cast<float4*>(h3 + (long)wave * D + sub * 4) = o;
        short4v hs, ls;
        short t0, t1, t2, t3, u0, u1, u2, u3;
        bsplit(o.x, t0, u0);
        bsplit(o.y, t1, u1);
        bsplit(o.z, t2, u2);
        bsplit(o.w, t3, u3);
        hs[0] = t0; hs[1] = t1; hs[2] = t2; hs[3] = t3;
        ls[0] = u0; ls[1] = u1; ls[2] = u2; ls[3] = u3;
        *reinterpret_cast<short4v*>(Hh + (long)wave * D + sub * 4) = hs;
        *reinterpret_cast<short4v*>(Hl + (long)wave * D + sub * 4) = ls;
    }
}

// ---------------- S = (Wb + Wb^T)/2 ----------------
__global__ void sym_kernel(const float* __restrict__ Wb, float* __restrict__ S) {
    int i = blockIdx.x * blockDim.x + threadIdx.x;
    if (i < 64 * 64) {
        int r = i >> 6, c = i & 63;
        S[i] = 0.5f * (Wb[r * 64 + c] + Wb[c * 64 + r]);
    }
}

// ---------------- zero the padded rows of the bf16 operands ----------------
__global__ void pad_zero(short* __restrict__ Th, short* __restrict__ Tl,
                         short* __restrict__ Hh, short* __restrict__ Hl,
                         int startRow, int padRows) {
    int i = blockIdx.x * blockDim.x + threadIdx.x;
    int tot = padRows * 64;
    if (i < tot) {
        long off = (long)startRow * 64 + i;
        Th[off] = 0; Tl[off] = 0; Hh[off] = 0; Hl[off] = 0;
    }
}

// ---------------- final: out = sigmoid(T @ H^T) via split-bf16 MFMA ----------------
// R12: epilogue uses nontemporal (streaming) stores so the 400 MB output
// stream does not write-allocate through L2 and evict the operand panels.
__global__ __launch_bounds__(256, 2) void final_mfma(
    const short* __restrict__ Th, const short* __restrict__ Tl,
    const short* __restrict__ Hh, const short* __restrict__ Hl,
    float* __restrict__ out, int n, int G, int ypx) {
    int bid = blockIdx.x;
    int xcd = bid & 7;
    int s4 = bid >> 3;
    int by = xcd * ypx + s4 % ypx;
    int bx = s4 / ypx;
    if (by >= G) return;

    int tid = threadIdx.x;
    int wave = tid >> 6, lane = tid & 63;
    int row0 = by * 128 + (wave >> 1) * 64;
    int col0 = bx * 128 + (wave & 1) * 64;
    int lrow = lane & 15;
    int koff = (lane >> 4) * 8;

    const short* ThB = Th + (long)(row0 + lrow) * 64 + koff;
    const short* TlB = Tl + (long)(row0 + lrow) * 64 + koff;
    const short* HhB = Hh + (long)(col0 + lrow) * 64 + koff;
    const short* HlB = Hl + (long)(col0 + lrow) * 64 + koff;

    f32x4 acc[4][4];
#pragma unroll
    for (int r = 0; r < 4; r++)
#pragma unroll
        for (int c = 0; c < 4; c++) acc[r][c] = (f32x4){0.f, 0.f, 0.f, 0.f};

#pragma unroll
    for (int ks = 0; ks < 2; ks++) {
        int kb = ks * 32;
        short8 ah[4], al[4];
#pragma unroll
        for (int r = 0; r < 4; r++) ah[r] = *reinterpret_cast<const short8*>(ThB + (long)(r * 16) * 64 + kb);
#pragma unroll
        for (int r = 0; r < 4; r++) al[r] = *reinterpret_cast<const short8*>(TlB + (long)(r * 16) * 64 + kb);

#pragma unroll
        for (int c = 0; c < 4; c++) {
            short8 bh = *reinterpret_cast<const short8*>(HhB + (long)(c * 16) * 64 + kb);
            short8 bl = *reinterpret_cast<const short8*>(HlB + (long)(c * 16) * 64 + kb);
#pragma unroll
            for (int r = 0; r < 4; r++)
                acc[r][c] = __builtin_amdgcn_mfma_f32_16x16x32_bf16(ah[r], bh, acc[r][c], 0, 0, 0);
#pragma unroll
            for (int r = 0; r < 4; r++)
                acc[r][c] = __builtin_amdgcn_mfma_f32_16x16x32_bf16(ah[r], bl, acc[r][c], 0, 0, 0);
#pragma unroll
            for (int r = 0; r < 4; r++)
                acc[r][c] = __builtin_amdgcn_mfma_f32_16x16x32_bf16(al[r], bh, acc[r][c], 0, 0, 0);
        }
    }

    // epilogue: C/D layout col = lane&15, row = (lane>>4)*4 + reg  [m89-verified]
    int orow = (lane >> 4) * 4;
    bool full = (row0 + 64 <= n) && (col0 + 64 <= n);
    if (full) {
#pragma unroll
        for (int r = 0; r < 4; r++) {
#pragma unroll
            for (int q = 0; q < 4; q++) {
                long base = (long)(row0 + r * 16 + orow + q) * n + col0 + lrow;
#pragma unroll
                for (int c = 0; c < 4; c++) {
                    float x = acc[r][c][q];
                    __builtin_nontemporal_store(__builtin_amdgcn_rcpf(1.f + __expf(-x)),
                                                out + base + c * 16);
                }
            }
        }
    } else {
#pragma unroll
        for (int r = 0; r < 4; r++) {
#pragma unroll
            for (int q = 0; q < 4; q++) {
                int i = row0 + r * 16 + orow + q;
                if (i < n) {
#pragma unroll
                    for (int c = 0; c < 4; c++) {
                        int j = col0 + c * 16 + lrow;
                        if (j < n) {
                            float x = acc[r][c][q];
                            __builtin_nontemporal_store(__builtin_amdgcn_rcpf(1.f + __expf(-x)),
                                                        out + (long)i * n + j);
                        }
                    }
                }
            }
        }
    }
}

// ---------------- launch ----------------
extern "C" void kernel_launch(void* const* d_in, const int* in_sizes, int n_in,
                              void* d_out, int out_size, void* d_ws, size_t ws_size,
                              hipStream_t stream) {
    const float* x    = (const float*)d_in[0];
    const int*   erow = (const int*)d_in[1];
    const int*   ecol = (const int*)d_in[2];
    const float* eval = (const float*)d_in[3];
    const float* W0   = (const float*)d_in[4];
    const float* W1   = (const float*)d_in[5];
    const float* W2   = (const float*)d_in[6];
    const float* Wb   = (const float*)d_in[7];
    float* out = (float*)d_out;

    int N = in_sizes[0] / 128;
    int E = in_sizes[1];
    int G = (N + 127) / 128;
    int Npad = G * 128;

    char* w = (char*)d_ws;
    size_t off = 0;
    auto alloc = [&](size_t bytes) -> void* {
        void* p = w + off;
        off += (bytes + 255) & ~(size_t)255;
        return p;
    };
    float* bufA    = (float*)alloc((size_t)N * 128 * 4);
    float* bufB    = (float*)alloc((size_t)N * 128 * 4);
    float* h3      = (float*)alloc((size_t)N * 64 * 4);
    float* S       = (float*)alloc(64 * 64 * 4);
    int*   colsort = (int*)alloc((size_t)E * 4);
    float* valsort = (float*)alloc((size_t)E * 4);
    int*   rowptr  = (int*)alloc((size_t)(N + 1) * 4);
    int*   cursor  = (int*)alloc((size_t)N * 4);
    int*   hist    = (int*)alloc((size_t)N * 4);
    short* Th      = (short*)alloc((size_t)Npad * 64 * 2);
    short* Tl      = (short*)alloc((size_t)Npad * 64 * 2);
    short* Hh      = (short*)alloc((size_t)Npad * 64 * 2);
    short* Hl      = (short*)alloc((size_t)Npad * 64 * 2);

    // CSR build
    zero_i32<<<(N + 255) / 256, 256, 0, stream>>>(hist, N);
    hist_kernel<<<(E + 255) / 256, 256, 0, stream>>>(erow, hist, E);
    scan_kernel<<<1, 1024, 0, stream>>>(hist, rowptr, cursor, N);
    scatter_kernel<<<(E + 255) / 256, 256, 0, stream>>>(erow, ecol, eval, cursor, colsort, valsort, E);

    int gb8 = (N + 7) / 8;
    int spmmG = (N + 3) / 4;
    // layer 1
    gemm_layer<128, 128><<<gb8, 128, 0, stream>>>(x, W0, bufB, N);
    spmm_elu_half<<<spmmG, 256, 0, stream>>>(rowptr, colsort, valsort, bufB, 128, bufA, 128, N);
    spmm_elu_half<<<spmmG, 256, 0, stream>>>(rowptr, colsort, valsort, bufB + 64, 128, bufA + 64, 128, N);
    // layer 2
    gemm_layer<128, 128><<<gb8, 128, 0, stream>>>(bufA, W1, bufB, N);
    spmm_elu_half<<<spmmG, 256, 0, stream>>>(rowptr, colsort, valsort, bufB, 128, bufA, 128, N);
    spmm_elu_half<<<spmmG, 256, 0, stream>>>(rowptr, colsort, valsort, bufB + 64, 128, bufA + 64, 128, N);
    // layer 3 (128 -> 64)
    gemm_layer<128, 64><<<gb8, 64, 0, stream>>>(bufA, W2, bufB, N);
    spmm_elu_split64<<<spmmG, 256, 0, stream>>>(rowptr, colsort, valsort, bufB, h3, Hh, Hl, N);

    sym_kernel<<<16, 256, 0, stream>>>(Wb, S);
    gemm_head<<<gb8, 64, 0, stream>>>(h3, S, Th, Tl, N);

    int padRows = Npad - N;
    if (padRows > 0)
        pad_zero<<<(padRows * 64 + 255) / 256, 256, 0, stream>>>(Th, Tl, Hh, Hl, N, padRows);

    int ypx = (G + 7) / 8;                 // y-tiles per XCD band
    int nwg = 8 * ypx * G;                 // padded; blocks with by>=G early-exit
    final_mfma<<<nwg, 256, 0, stream>>>(Th, Tl, Hh, Hl, out, N, G, ypx);
}